// Round 1
// baseline (172.222 us; speedup 1.0000x reference)
//
#include <hip/hip_runtime.h>
#include <math.h>

#define N 4096
#define NB 2
#define THRESHOLD_FACTOR 1.25

// ---------------------------------------------------------------------------
// Kernel 1: per-batch mean/std of dist_sq via separable sums (O(n) not O(n^2)).
// dist[s,t] = a_s*A_t + b_s*B_t with a=x^2, b=y^2, A=(1-x)^2, B=(1-y)^2.
// sum d   = Sa*SA + Sb*SB
// sum d^2 = Saa*SAA + Sbb*SBB + 2*Sab*SAB
// One block per batch, double accumulation.
// ---------------------------------------------------------------------------
__global__ __launch_bounds__(256) void stats_kernel(const float* __restrict__ r,
                                                    float* __restrict__ thr) {
    int b = blockIdx.x;
    const float* rb = r + (size_t)b * N * 2;
    int tid = threadIdx.x;

    double s[10];
#pragma unroll
    for (int i = 0; i < 10; ++i) s[i] = 0.0;

    for (int idx = tid; idx < N; idx += 256) {
        float x = rb[idx * 2 + 0];
        float y = rb[idx * 2 + 1];
        double a  = (double)x * (double)x;
        double bb = (double)y * (double)y;
        double ax = 1.0 - (double)x;
        double by = 1.0 - (double)y;
        double A  = ax * ax;
        double Bv = by * by;
        s[0] += a;      s[1] += bb;     s[2] += A;      s[3] += Bv;
        s[4] += a * a;  s[5] += bb * bb; s[6] += a * bb;
        s[7] += A * A;  s[8] += Bv * Bv; s[9] += A * Bv;
    }

    __shared__ double red[256];
    __shared__ double tot[10];
    for (int q = 0; q < 10; ++q) {
        red[tid] = s[q];
        __syncthreads();
        for (int st = 128; st > 0; st >>= 1) {
            if (tid < st) red[tid] += red[tid + st];
            __syncthreads();
        }
        if (tid == 0) tot[q] = red[0];
        __syncthreads();
    }

    if (tid == 0) {
        double pairs = (double)N * (double)N;
        double sum_d  = tot[0] * tot[2] + tot[1] * tot[3];
        double sum_d2 = tot[4] * tot[7] + tot[5] * tot[8] + 2.0 * tot[6] * tot[9];
        double mean = sum_d / pairs;
        double var = (sum_d2 - sum_d * sum_d / pairs) / (pairs - 1.0);
        double sd = sqrt(var);
        if (sd < 1e-6) sd = 1e-6;
        thr[b] = (float)(mean + THRESHOLD_FACTOR * sd);
    }
}

// ---------------------------------------------------------------------------
// Kernel 2: one block per (b,s) row. Each thread computes 16 t-entries
// (4 groups of 4 consecutive t for float4 stores), block-reduces the row sum,
// normalizes, and writes coalesced float4.
// ---------------------------------------------------------------------------
__global__ __launch_bounds__(256) void attn_kernel(const float* __restrict__ r,
                                                   const float* __restrict__ thr,
                                                   float* __restrict__ out) {
    int row = blockIdx.x;          // b*N + s
    int b = row >> 12;             // N = 4096
    int s = row & (N - 1);
    const float* rb = r + (size_t)b * N * 2;

    float rsx = rb[s * 2 + 0];
    float rsy = rb[s * 2 + 1];
    float threshold = thr[b];

    int tid = threadIdx.x;
    float vals[16];
    float sum = 0.0f;

#pragma unroll
    for (int g = 0; g < 4; ++g) {
        int t0 = g * 1024 + tid * 4;
        // r[b, t0..t0+3, :] = 8 consecutive floats = 2 float4 loads (coalesced)
        float4 p0 = *(const float4*)(rb + (size_t)t0 * 2);
        float4 p1 = *(const float4*)(rb + (size_t)t0 * 2 + 4);
        float tx[4] = {p0.x, p0.z, p1.x, p1.z};
        float ty[4] = {p0.y, p0.w, p1.y, p1.w};
#pragma unroll
        for (int k = 0; k < 4; ++k) {
            // diff = -r_s*r_t + r_s
            float dx = fmaf(-rsx, tx[k], rsx);
            float dy = fmaf(-rsy, ty[k], rsy);
            float d = dx * dx + dy * dy;
            // cos(atan2(dy,dx)) = dx / sqrt(d); atan2(0,0)=0 -> cos=1
            float c = (d > 0.0f) ? (dx / sqrtf(d)) : 1.0f;
            float fb = 0.5f * (1.0f + c) * expf(-d);
            float v = (d <= threshold) ? fb : 0.0f;
            vals[g * 4 + k] = v;
            sum += v;
        }
    }

    // block-level row-sum reduction: wave64 shuffle, then LDS across 4 waves
#pragma unroll
    for (int off = 32; off > 0; off >>= 1) sum += __shfl_down(sum, off, 64);
    __shared__ float wsum[4];
    int lane = tid & 63;
    int wid = tid >> 6;
    if (lane == 0) wsum[wid] = sum;
    __syncthreads();
    float total = wsum[0] + wsum[1] + wsum[2] + wsum[3];
    float inv = 1.0f / (total + 1e-8f);

    float4* outp = (float4*)(out + (size_t)row * N);
#pragma unroll
    for (int g = 0; g < 4; ++g) {
        int t0 = g * 1024 + tid * 4;
        float4 v4;
        v4.x = vals[g * 4 + 0] * inv;
        v4.y = vals[g * 4 + 1] * inv;
        v4.z = vals[g * 4 + 2] * inv;
        v4.w = vals[g * 4 + 3] * inv;
        outp[t0 >> 2] = v4;
    }
}

extern "C" void kernel_launch(void* const* d_in, const int* in_sizes, int n_in,
                              void* d_out, int out_size, void* d_ws, size_t ws_size,
                              hipStream_t stream) {
    const float* r = (const float*)d_in[0];
    float* out = (float*)d_out;
    float* thr = (float*)d_ws;  // 2 floats

    stats_kernel<<<NB, 256, 0, stream>>>(r, thr);
    attn_kernel<<<NB * N, 256, 0, stream>>>(r, thr, out);
}

// Round 2
// 143.861 us; speedup vs baseline: 1.1971x; 1.1971x over previous
//
#include <hip/hip_runtime.h>
#include <math.h>

#define N 4096
#define NB 2
#define THRESHOLD_FACTOR 1.25

// ---------------------------------------------------------------------------
// Kernel 1: per-batch mean/std of dist_sq via separable sums (O(n) not O(n^2)).
// dist[s,t] = a_s*A_t + b_s*B_t with a=x^2, b=y^2, A=(1-x)^2, B=(1-y)^2.
// sum d   = Sa*SA + Sb*SB
// sum d^2 = Saa*SAA + Sbb*SBB + 2*Sab*SAB
// One block per batch, double accumulation, single-pass LDS tree (8 barriers).
// ---------------------------------------------------------------------------
__global__ __launch_bounds__(256) void stats_kernel(const float* __restrict__ r,
                                                    float* __restrict__ thr) {
    int b = blockIdx.x;
    const float* rb = r + (size_t)b * N * 2;
    int tid = threadIdx.x;

    double s[10];
#pragma unroll
    for (int i = 0; i < 10; ++i) s[i] = 0.0;

    for (int idx = tid; idx < N; idx += 256) {
        float x = rb[idx * 2 + 0];
        float y = rb[idx * 2 + 1];
        double a  = (double)x * (double)x;
        double bb = (double)y * (double)y;
        double ax = 1.0 - (double)x;
        double by = 1.0 - (double)y;
        double A  = ax * ax;
        double Bv = by * by;
        s[0] += a;      s[1] += bb;      s[2] += A;      s[3] += Bv;
        s[4] += a * a;  s[5] += bb * bb; s[6] += a * bb;
        s[7] += A * A;  s[8] += Bv * Bv; s[9] += A * Bv;
    }

    // one-pass tree reduction over all 10 quantities
    __shared__ double red[256][10];
#pragma unroll
    for (int q = 0; q < 10; ++q) red[tid][q] = s[q];
    __syncthreads();
    for (int st = 128; st > 0; st >>= 1) {
        if (tid < st) {
#pragma unroll
            for (int q = 0; q < 10; ++q) red[tid][q] += red[tid + st][q];
        }
        __syncthreads();
    }

    if (tid == 0) {
        double t0 = red[0][0], t1 = red[0][1], t2 = red[0][2], t3 = red[0][3];
        double t4 = red[0][4], t5 = red[0][5], t6 = red[0][6];
        double t7 = red[0][7], t8 = red[0][8], t9 = red[0][9];
        double pairs = (double)N * (double)N;
        double sum_d  = t0 * t2 + t1 * t3;
        double sum_d2 = t4 * t7 + t5 * t8 + 2.0 * t6 * t9;
        double mean = sum_d / pairs;
        double var = (sum_d2 - sum_d * sum_d / pairs) / (pairs - 1.0);
        double sd = sqrt(var);
        if (sd < 1e-6) sd = 1e-6;
        thr[b] = (float)(mean + THRESHOLD_FACTOR * sd);
    }
}

// ---------------------------------------------------------------------------
// Kernel 2: one block per (b,s) row. Each thread computes 16 t-entries
// (4 groups of 4 consecutive t for float4 stores), block-reduces the row sum,
// normalizes, and writes coalesced float4. All math via native HW ops:
// v_exp_f32 (__expf), v_rsq_f32, v_rcp_f32 — no libm guarded sequences.
// ---------------------------------------------------------------------------
__global__ __launch_bounds__(256) void attn_kernel(const float* __restrict__ r,
                                                   const float* __restrict__ thr,
                                                   float* __restrict__ out) {
    int row = blockIdx.x;          // b*N + s
    int b = row >> 12;             // N = 4096
    int s = row & (N - 1);
    const float* rb = r + (size_t)b * N * 2;

    float rsx = rb[s * 2 + 0];
    float rsy = rb[s * 2 + 1];
    float threshold = thr[b];

    int tid = threadIdx.x;
    float vals[16];
    float sum = 0.0f;

#pragma unroll
    for (int g = 0; g < 4; ++g) {
        int t0 = g * 1024 + tid * 4;
        // r[b, t0..t0+3, :] = 8 consecutive floats = 2 float4 loads (coalesced)
        float4 p0 = *(const float4*)(rb + (size_t)t0 * 2);
        float4 p1 = *(const float4*)(rb + (size_t)t0 * 2 + 4);
        float tx[4] = {p0.x, p0.z, p1.x, p1.z};
        float ty[4] = {p0.y, p0.w, p1.y, p1.w};
#pragma unroll
        for (int k = 0; k < 4; ++k) {
            // diff = -r_s*r_t + r_s
            float dx = fmaf(-rsx, tx[k], rsx);
            float dy = fmaf(-rsy, ty[k], rsy);
            float d = fmaf(dx, dx, dy * dy);
            // cos(atan2(dy,dx)) = dx * rsqrt(d); atan2(0,0)=0 -> cos=1
            float c = (d > 0.0f) ? (dx * __builtin_amdgcn_rsqf(d)) : 1.0f;
            // 0.5*(1+c)*exp(-d): v_exp_f32-based fast exp
            float e = __expf(-d);
            float fb = fmaf(0.5f, c * e, 0.5f * e);
            float v = (d <= threshold) ? fb : 0.0f;
            vals[g * 4 + k] = v;
            sum += v;
        }
    }

    // block-level row-sum reduction: wave64 shuffle, then LDS across 4 waves
#pragma unroll
    for (int off = 32; off > 0; off >>= 1) sum += __shfl_down(sum, off, 64);
    __shared__ float wsum[4];
    int lane = tid & 63;
    int wid = tid >> 6;
    if (lane == 0) wsum[wid] = sum;
    __syncthreads();
    float total = wsum[0] + wsum[1] + wsum[2] + wsum[3];
    float inv = __builtin_amdgcn_rcpf(total + 1e-8f);

    float4* outp = (float4*)(out + (size_t)row * N);
#pragma unroll
    for (int g = 0; g < 4; ++g) {
        int t0 = g * 1024 + tid * 4;
        float4 v4;
        v4.x = vals[g * 4 + 0] * inv;
        v4.y = vals[g * 4 + 1] * inv;
        v4.z = vals[g * 4 + 2] * inv;
        v4.w = vals[g * 4 + 3] * inv;
        outp[t0 >> 2] = v4;
    }
}

extern "C" void kernel_launch(void* const* d_in, const int* in_sizes, int n_in,
                              void* d_out, int out_size, void* d_ws, size_t ws_size,
                              hipStream_t stream) {
    const float* r = (const float*)d_in[0];
    float* out = (float*)d_out;
    float* thr = (float*)d_ws;  // 2 floats

    stats_kernel<<<NB, 256, 0, stream>>>(r, thr);
    attn_kernel<<<NB * N, 256, 0, stream>>>(r, thr, out);
}